// Round 5
// baseline (668.464 us; speedup 1.0000x reference)
//
#include <hip/hip_runtime.h>

// LiftSplatShoot voxel pooling, B=1, N=6, D=41, H=64, W=176, C=32, grid 200x200x1.
// nprime = 2,770,944 points. rank = ix*200 + iy (nx2=1, B=1).
// out[c*40000 + ix*200 + iy] = sum over points in voxel (ix,iy) of x[p][c].
//
// R6 (3921->611us): linked lists + wave-per-voxel gather killed the 88.7M
//   contended f32 atomics.
// R8 (724us): CSR. rocprof: count=289us, gather_csr=217us @740GB/s, VALU 6%,
//   VGPR=12. R9 (618us): 8 parallel chains == 2 chains -> gather was NEVER
//   chase-bound. Diagnosis: ~1 memory op in flight per wave. The per-iter
//   validity BRANCH blocked compiler pipelining (VGPR=12); build/count
//   threads issue ONE atomic and wait for its return (~900cy round trip,
//   1-deep MLP).
// R10: explicit MLP, branch-free. count8: 8 points/thread, 8 independent
//   fetch_adds in flight. gather_p: 8-deep manual unroll, clamp instead of
//   guard -> 16 row loads (2KB) in flight per wave. Poison fill (215us,
//   1.419GB) is a fixed harness floor we cannot touch.

#define NVOX   40000
#define NCH    32
#define MAXPTS 128   // Poisson mean ~52/voxel, sd 7.2; 128 = +10.5 sigma.
                     // Overflow (never expected) -> f32 atomics into extra[].

__device__ __forceinline__ void atomic_add_agent(float* p, float v) {
    __hip_atomic_fetch_add(p, v, __ATOMIC_RELAXED, __HIP_MEMORY_SCOPE_AGENT);
}

__device__ __forceinline__ int voxel_of(const float* __restrict__ geom, int p) {
    // Exact reference arithmetic: t = (g - (bx - dx/2)) / dx, trunc toward zero.
    float gx = geom[3 * (size_t)p + 0];
    float gy = geom[3 * (size_t)p + 1];
    float gz = geom[3 * (size_t)p + 2];
    float tx = (gx + 50.0f) / 0.5f;   // lo_x = -50 exact; /0.5 exact
    float ty = (gy + 50.0f) / 0.5f;
    float tz = (gz + 10.0f) / 20.0f;  // correctly-rounded IEEE f32 division
    int ix = (int)tx;  // trunc toward zero == astype(int32); (-1,0) -> 0 kept
    int iy = (int)ty;
    int iz = (int)tz;
    if (!((ix >= 0) && (ix < 200) && (iy >= 0) && (iy < 200) && (iz == 0)))
        return -1;
    return ix * 200 + iy;
}

// ---------------- tier 1: CSR build + pipelined gather ---------------------

// cnt:[NVOX] counts, extra:[NVOX*NCH] overflow acc (both memset 0),
// bucket:[NVOX*MAXPTS] point indices (no init).
// Each thread handles 8 points at stride nthreads (coalesced geom reads);
// the 8 fetch_adds are independent -> 8x atomic MLP.
__global__ void __launch_bounds__(256)
lss_count8(const float* __restrict__ geom, const float* __restrict__ x,
           int* __restrict__ cnt, float* __restrict__ extra,
           int* __restrict__ bucket, int nprime, int nthreads) {
    int t = blockIdx.x * blockDim.x + threadIdx.x;
    if (t >= nthreads) return;

    int pv[8], vv[8], sl[8];
    #pragma unroll
    for (int j = 0; j < 8; ++j) {
        int p = t + j * nthreads;
        pv[j] = p;
        vv[j] = (p < nprime) ? voxel_of(geom, p) : -1;
    }
    #pragma unroll
    for (int j = 0; j < 8; ++j) {
        sl[j] = 0;
        if (vv[j] >= 0)   // independent atomics; returns consumed next loop
            sl[j] = __hip_atomic_fetch_add(&cnt[vv[j]], 1,
                        __ATOMIC_RELAXED, __HIP_MEMORY_SCOPE_AGENT);
    }
    #pragma unroll
    for (int j = 0; j < 8; ++j) {
        if (vv[j] >= 0) {
            if (sl[j] < MAXPTS) {
                bucket[(size_t)vv[j] * MAXPTS + sl[j]] = pv[j];
            } else {  // statistically unreachable; correctness insurance
                const float* row = x + (size_t)pv[j] * NCH;
                for (int k = 0; k < NCH; ++k)
                    atomic_add_agent(&extra[(size_t)vv[j] * NCH + k], row[k]);
            }
        }
    }
}

// One wave per voxel; half h walks slots h, h+2, ... (parity split).
// Body is branch-free: 8 index loads then 8 row loads in flight, clamp
// (never triggered in a sane run) instead of a pipeline-killing guard.
__global__ void __launch_bounds__(256)
lss_gather_p(const float* __restrict__ x, const int* __restrict__ cnt,
             const float* __restrict__ extra, const int* __restrict__ bucket,
             float* __restrict__ out, int nprime) {
    int wv = blockIdx.x * (blockDim.x >> 6) + (threadIdx.x >> 6);  // voxel
    if (wv >= NVOX) return;
    int lane = threadIdx.x & 63;
    int half = lane >> 5;
    int c    = lane & 31;

    int total = cnt[wv];
    int n = total < MAXPTS ? total : MAXPTS;
    const int* base = bucket + (size_t)wv * MAXPTS;
    unsigned pmax = (unsigned)(nprime - 1);

    float acc = 0.0f;
    int i = half;
    for (; i + 14 < n; i += 16) {   // 8 slots per half per block
        int p0 = base[i +  0], p1 = base[i +  2], p2 = base[i +  4], p3 = base[i +  6];
        int p4 = base[i +  8], p5 = base[i + 10], p6 = base[i + 12], p7 = base[i + 14];
        p0 = (int)min((unsigned)p0, pmax); p1 = (int)min((unsigned)p1, pmax);
        p2 = (int)min((unsigned)p2, pmax); p3 = (int)min((unsigned)p3, pmax);
        p4 = (int)min((unsigned)p4, pmax); p5 = (int)min((unsigned)p5, pmax);
        p6 = (int)min((unsigned)p6, pmax); p7 = (int)min((unsigned)p7, pmax);
        float v0 = x[(size_t)p0 * NCH + c], v1 = x[(size_t)p1 * NCH + c];
        float v2 = x[(size_t)p2 * NCH + c], v3 = x[(size_t)p3 * NCH + c];
        float v4 = x[(size_t)p4 * NCH + c], v5 = x[(size_t)p5 * NCH + c];
        float v6 = x[(size_t)p6 * NCH + c], v7 = x[(size_t)p7 * NCH + c];
        acc += ((v0 + v1) + (v2 + v3)) + ((v4 + v5) + (v6 + v7));
    }
    for (; i < n; i += 2) {         // tail, <8 iters per half
        int p = (int)min((unsigned)base[i], pmax);
        acc += x[(size_t)p * NCH + c];
    }
    acc += __shfl_xor(acc, 32);     // combine the two halves
    if (lane < 32) {
        float r = acc;
        if (total > MAXPTS) r += extra[(size_t)wv * NCH + c];
        out[(size_t)c * NVOX + wv] = r;   // (C, 200, 200), every voxel written
    }
}

// ---------------- tier 2: 2-chain linked lists (proven R7, 611us) ----------

__global__ void __launch_bounds__(256)
lss_build(const float* __restrict__ geom, int* __restrict__ head2,
          int* __restrict__ next, int nprime) {
    int p = blockIdx.x * blockDim.x + threadIdx.x;
    if (p >= nprime) return;
    int v = voxel_of(geom, p);
    if (v < 0) return;
    int slot = (p & 1) * NVOX + v;
    int old = __hip_atomic_exchange(&head2[slot], p,
                                    __ATOMIC_RELAXED, __HIP_MEMORY_SCOPE_AGENT);
    next[p] = old;
}

__global__ void __launch_bounds__(256)
lss_gather(const float* __restrict__ x, const int* __restrict__ head2,
           const int* __restrict__ next, float* __restrict__ out, int nprime) {
    int wv = blockIdx.x * (blockDim.x >> 6) + (threadIdx.x >> 6);
    if (wv >= NVOX) return;
    int lane = threadIdx.x & 63;
    int half = lane >> 5;
    int c    = lane & 31;

    float acc = 0.0f;
    int p = head2[half * NVOX + wv];
    int left = nprime;
    while (p >= 0 && p < nprime && left-- > 0) {
        acc += x[(size_t)p * NCH + c];
        p = next[p];
    }
    acc += __shfl_xor(acc, 32);
    if (lane < 32)
        out[(size_t)c * NVOX + wv] = acc;
}

// ---------------- tier 3: atomic scatter (proven R5) -----------------------

__global__ void __launch_bounds__(256)
lss_scatter(const float* __restrict__ geom,
            const float* __restrict__ x,
            float* __restrict__ acc, int nprime, int c0, int cg) {
    int p = blockIdx.x * blockDim.x + threadIdx.x;
    if (p >= nprime) return;
    int v = voxel_of(geom, p);
    if (v < 0) return;

    float* dst = acc + (size_t)v * cg;
    const float* row = x + (size_t)p * NCH + c0;

    int k4 = cg >> 2;
    const float4* rv = (const float4*)row;
    for (int k = 0; k < k4; ++k) {
        float4 vv = rv[k];
        atomic_add_agent(dst + 4 * k + 0, vv.x);
        atomic_add_agent(dst + 4 * k + 1, vv.y);
        atomic_add_agent(dst + 4 * k + 2, vv.z);
        atomic_add_agent(dst + 4 * k + 3, vv.w);
    }
    for (int k = k4 << 2; k < cg; ++k)
        atomic_add_agent(dst + k, row[k]);
}

__global__ void __launch_bounds__(256)
lss_finalize(const float* __restrict__ acc, float* __restrict__ out,
             int c0, int cg) {
    int t = blockIdx.x * blockDim.x + threadIdx.x;
    if (t >= NVOX * cg) return;
    int cl = t / NVOX;
    int s  = t - cl * NVOX;
    out[(size_t)(c0 + cl) * NVOX + s] = acc[(size_t)s * cg + cl];
}

// ---------------------------------------------------------------------------

extern "C" void kernel_launch(void* const* d_in, const int* in_sizes, int n_in,
                              void* d_out, int out_size, void* d_ws, size_t ws_size,
                              hipStream_t stream) {
    const float* geom = (const float*)d_in[0];
    const float* x    = (const float*)d_in[1];
    int gsz = in_sizes[0], xsz = in_sizes[1];
    if (gsz > xsz) {  // defensive: geom (nprime*3) is the smaller input
        const float* tmp = geom; geom = x; x = tmp;
        int t2 = gsz; gsz = xsz; xsz = t2;
    }
    float* out = (float*)d_out;
    int nprime = xsz / NCH;  // 2,770,944
    int threads = 256;

    // tier 1: CSR buckets. cnt | extra | bucket.
    size_t need_csr = ((size_t)NVOX + (size_t)NVOX * NCH
                       + (size_t)NVOX * MAXPTS) * 4;  // ~25.9 MB
    if (ws_size >= need_csr) {
        int*   cnt    = (int*)d_ws;
        float* extra  = (float*)(cnt + NVOX);
        int*   bucket = (int*)(extra + (size_t)NVOX * NCH);
        // cnt + extra contiguous -> one zeroing memset (5.28 MB, ~1us)
        hipMemsetAsync(cnt, 0, ((size_t)NVOX + (size_t)NVOX * NCH) * 4, stream);
        int nthreads = (nprime + 7) / 8;   // 346,368 (nprime divisible by 8)
        int blocks_cnt = (nthreads + threads - 1) / threads;
        lss_count8<<<blocks_cnt, threads, 0, stream>>>(geom, x, cnt, extra,
                                                       bucket, nprime, nthreads);
        int blocks_g = (NVOX + (threads / 64) - 1) / (threads / 64);  // 10000
        lss_gather_p<<<blocks_g, threads, 0, stream>>>(x, cnt, extra, bucket,
                                                       out, nprime);
        return;
    }

    // tier 2: 2-chain linked lists
    size_t need_ll = (size_t)(2 * NVOX + nprime) * sizeof(int);  // ~11.4 MB
    if (ws_size >= need_ll) {
        int* head2 = (int*)d_ws;
        int* next  = head2 + 2 * NVOX;
        hipMemsetAsync(head2, 0xFF, (size_t)2 * NVOX * sizeof(int), stream);
        int blocks_build = (nprime + threads - 1) / threads;
        lss_build<<<blocks_build, threads, 0, stream>>>(geom, head2, next, nprime);
        int blocks_gather = (NVOX + (threads / 64) - 1) / (threads / 64);
        lss_gather<<<blocks_gather, threads, 0, stream>>>(x, head2, next, out, nprime);
        return;
    }

    // tier 3: channel-grouped atomic scatter
    float* acc = (float*)d_ws;
    int cg = NCH;
    while (cg > 1 && (size_t)NVOX * cg * sizeof(float) > ws_size) cg >>= 1;
    int blocks_scatter = (nprime + threads - 1) / threads;
    for (int c0 = 0; c0 < NCH; c0 += cg) {
        hipMemsetAsync(acc, 0, (size_t)NVOX * cg * sizeof(float), stream);
        lss_scatter<<<blocks_scatter, threads, 0, stream>>>(geom, x, acc, nprime, c0, cg);
        int total = NVOX * cg;
        lss_finalize<<<(total + threads - 1) / threads, threads, 0, stream>>>(acc, out, c0, cg);
    }
}